// Round 7
// baseline (568.313 us; speedup 1.0000x reference)
//
#include <hip/hip_runtime.h>
#include <hip/hip_bf16.h>

typedef __bf16 bf16x8 __attribute__((ext_vector_type(8)));
typedef float  f32x4  __attribute__((ext_vector_type(4)));

#define GRU_H 128
#define ROWS  64

__device__ inline float sigmoidf_(float x) { return 1.f / (1.f + __expf(-x)); }
__device__ inline float tanhf_(float x)    { return 1.f - 2.f / (__expf(2.f * x) + 1.f); }

__device__ inline bf16x8 cvt8(float4 a, float4 b) {
    bf16x8 r;
    r[0] = (__bf16)a.x; r[1] = (__bf16)a.y; r[2] = (__bf16)a.z; r[3] = (__bf16)a.w;
    r[4] = (__bf16)b.x; r[5] = (__bf16)b.y; r[6] = (__bf16)b.z; r[7] = (__bf16)b.w;
    return r;
}

// ---- prep1 (24 blocks x 512): weights f32 -> bf16 lane-ordered MFMA fragments
// in ws; also clears the scatter bitmap.
// frag t = ((wave*6+g)*4+ks)*64+lane : 8 bf16 of W[(g%3)*128+col][ks*32+lg*8 ..+7]
__global__ __launch_bounds__(512) void prep_weights(
    const float* __restrict__ W_ih, const float* __restrict__ W_hh,
    bf16x8* __restrict__ frags, unsigned* __restrict__ bitmap, int nwords)
{
    const int t = blockIdx.x * 512 + threadIdx.x;       // 0..12287
    for (int i = t; i < nwords; i += 12288) bitmap[i] = 0u;
    const int lane = t & 63;
    const int ks   = (t >> 6) & 3;
    const int r    = t >> 8;                            // 0..47
    const int g    = r % 6;
    const int wave = r / 6;
    const int col  = wave * 16 + (lane & 15);
    const int lg   = lane >> 4;
    const int gg   = (g < 3) ? g : g - 3;
    const float* src = ((g < 3) ? W_ih : W_hh) + (size_t)(gg * GRU_H + col) * GRU_H + ks * 32 + lg * 8;
    float4 a = *reinterpret_cast<const float4*>(src);
    float4 b = *reinterpret_cast<const float4*>(src + 4);
    frags[t] = cvt8(a, b);
}

// ---- prep2: mark scatter-target rows (copy path skips exactly these)
__global__ __launch_bounds__(512) void set_bits(const int* __restrict__ ids, int B,
                                                unsigned* __restrict__ bitmap)
{
    const int i = blockIdx.x * 512 + threadIdx.x;
    if (i < B) {
        const int id = ids[i];
        atomicOr(&bitmap[id >> 5], 1u << (id & 31));
    }
}

// ---- fused: GRU update+scatter (chunk grid-stride), then bitmap-guarded
// pass-through copy. 512 thr = 8 waves; wave w owns 16-col tile. W_ih frags
// persistent in regs (48 VGPR); W_hh frags streamed from L2-hot ws per ks.
// h staged to LDS as bf16 (MFMA) AND f32 (exact epilogue); x staged as bf16.
// All tiles XOR-swizzled at 16B granularity: byte ^= (row&7)<<4.
__global__ __launch_bounds__(512, 4) void fused_kernel(
    const int*    __restrict__ node_ids,
    const float*  __restrict__ messages,
    const float*  __restrict__ memory,
    const bf16x8* __restrict__ frags,
    const float*  __restrict__ b_ih,
    const float*  __restrict__ b_hh,
    const unsigned* __restrict__ bitmap,
    float*        __restrict__ out,
    int B, int N)
{
    __shared__ __align__(16) unsigned char xs_raw[ROWS * 256];  // bf16 x   [64][128]
    __shared__ __align__(16) unsigned char hb_raw[ROWS * 256];  // bf16 h   [64][128]
    __shared__ __align__(16) unsigned char hf_raw[ROWS * 512];  // f32  h   [64][128]
    __shared__ int ids[ROWS];

    const int tid  = threadIdx.x;
    const int wave = tid >> 6;
    const int lane = tid & 63;
    const int l15  = lane & 15;
    const int lg   = lane >> 4;
    const int col  = wave * 16 + l15;

    // persistent W_ih fragments (12 x 16B coalesced loads, 48 VGPR)
    bf16x8 bfih[3][4];
    #pragma unroll
    for (int g = 0; g < 3; ++g)
        #pragma unroll
        for (int ks = 0; ks < 4; ++ks)
            bfih[g][ks] = frags[((wave * 6 + g) * 4 + ks) * 64 + lane];

    const float bi_r = b_ih[col], bi_z = b_ih[GRU_H + col], bi_n = b_ih[2 * GRU_H + col];
    const float bh_r = b_hh[col], bh_z = b_hh[GRU_H + col], bh_n = b_hh[2 * GRU_H + col];

    const int nchunks = (B + ROWS - 1) / ROWS;
    for (int c = blockIdx.x; c < nchunks; c += gridDim.x) {
        const int rb = c * ROWS;

        // stage h: 1024 slots (row, c8); each slot = 8 floats -> f32 pair + bf16x8
        #pragma unroll
        for (int s = 0; s < 2; ++s) {
            const int slot = tid + s * 512;
            const int row  = slot >> 4;
            const int c8   = slot & 15;
            const int grow = rb + row;
            const int sw   = (row & 7) << 4;
            float4 a = {0.f, 0.f, 0.f, 0.f}, b = {0.f, 0.f, 0.f, 0.f};
            if (grow < B) {
                const int gid = node_ids[grow];
                if (c8 == 0) ids[row] = gid;
                const float* p = &memory[(size_t)gid * GRU_H + c8 * 8];
                a = *reinterpret_cast<const float4*>(p);
                b = *reinterpret_cast<const float4*>(p + 4);
            }
            *reinterpret_cast<float4*>(&hf_raw[row * 512 + (((c8 * 2) * 16) ^ sw)]) = a;
            *reinterpret_cast<float4*>(&hf_raw[row * 512 + (((c8 * 2 + 1) * 16) ^ sw)]) = b;
            *reinterpret_cast<bf16x8*>(&hb_raw[row * 256 + ((c8 * 16) ^ sw)]) = cvt8(a, b);
        }
        // stage x: bf16 only
        #pragma unroll
        for (int s = 0; s < 2; ++s) {
            const int slot = tid + s * 512;
            const int row  = slot >> 4;
            const int c8   = slot & 15;
            const int grow = rb + row;
            const int sw   = (row & 7) << 4;
            float4 a = {0.f, 0.f, 0.f, 0.f}, b = {0.f, 0.f, 0.f, 0.f};
            if (grow < B) {
                const float* p = &messages[(size_t)grow * GRU_H + c8 * 8];
                a = *reinterpret_cast<const float4*>(p);
                b = *reinterpret_cast<const float4*>(p + 4);
            }
            *reinterpret_cast<bf16x8*>(&xs_raw[row * 256 + ((c8 * 16) ^ sw)]) = cvt8(a, b);
        }
        __syncthreads();

        #pragma unroll
        for (int sub = 0; sub < 4; ++sub) {
            const int arow = sub * 16 + l15;
            const int sw   = (arow & 7) << 4;

            f32x4 acc0 = {0.f,0.f,0.f,0.f}, acc1 = acc0, acc2 = acc0,
                  acc3 = acc0, acc4 = acc0, acc5 = acc0;

            #pragma unroll
            for (int ks = 0; ks < 4; ++ks) {
                const bf16x8 ax = *reinterpret_cast<const bf16x8*>(
                    &xs_raw[arow * 256 + (((ks * 4 + lg) * 16) ^ sw)]);
                const bf16x8 ah = *reinterpret_cast<const bf16x8*>(
                    &hb_raw[arow * 256 + (((ks * 4 + lg) * 16) ^ sw)]);
                // streamed W_hh fragments (L2-hot, coalesced)
                const bf16x8 w3 = frags[((wave * 6 + 3) * 4 + ks) * 64 + lane];
                const bf16x8 w4 = frags[((wave * 6 + 4) * 4 + ks) * 64 + lane];
                const bf16x8 w5 = frags[((wave * 6 + 5) * 4 + ks) * 64 + lane];
                acc0 = __builtin_amdgcn_mfma_f32_16x16x32_bf16(ax, bfih[0][ks], acc0, 0, 0, 0);
                acc1 = __builtin_amdgcn_mfma_f32_16x16x32_bf16(ax, bfih[1][ks], acc1, 0, 0, 0);
                acc2 = __builtin_amdgcn_mfma_f32_16x16x32_bf16(ax, bfih[2][ks], acc2, 0, 0, 0);
                acc3 = __builtin_amdgcn_mfma_f32_16x16x32_bf16(ah, w3, acc3, 0, 0, 0);
                acc4 = __builtin_amdgcn_mfma_f32_16x16x32_bf16(ah, w4, acc4, 0, 0, 0);
                acc5 = __builtin_amdgcn_mfma_f32_16x16x32_bf16(ah, w5, acc5, 0, 0, 0);
            }

            // D layout: col=l15, row=lg*4+r
            #pragma unroll
            for (int r = 0; r < 4; ++r) {
                const int row  = sub * 16 + lg * 4 + r;
                const int grow = rb + row;
                if (grow < B) {
                    const int gid = ids[row];
                    const int swr = (row & 7) << 4;
                    const float h = *reinterpret_cast<const float*>(
                        &hf_raw[row * 512 + ((((col >> 2) * 16) ^ swr) + (col & 3) * 4)]);
                    const float rg = sigmoidf_((acc0[r] + bi_r) + (acc3[r] + bh_r));
                    const float zg = sigmoidf_((acc1[r] + bi_z) + (acc4[r] + bh_z));
                    const float ng = tanhf_((acc2[r] + bi_n) + rg * (acc5[r] + bh_n));
                    out[(size_t)gid * GRU_H + col] = (1.f - zg) * ng + zg * h;
                }
            }
        }
        __syncthreads();
    }

    // ---- copy phase: rows not written by the scatter
    const float4* src4 = reinterpret_cast<const float4*>(memory);
    float4*       dst4 = reinterpret_cast<float4*>(out);
    const size_t n4     = (size_t)N * (GRU_H / 4);
    const size_t stride = (size_t)gridDim.x * blockDim.x;
    for (size_t j = (size_t)blockIdx.x * blockDim.x + tid; j < n4; j += stride) {
        const int row = (int)(j >> 5);
        if (!((bitmap[row >> 5] >> (row & 31)) & 1u))
            dst4[j] = src4[j];
    }
}

extern "C" void kernel_launch(void* const* d_in, const int* in_sizes, int n_in,
                              void* d_out, int out_size, void* d_ws, size_t ws_size,
                              hipStream_t stream) {
    const int*   node_ids = (const int*)d_in[0];
    const float* messages = (const float*)d_in[1];
    const float* memory   = (const float*)d_in[2];
    const float* W_ih     = (const float*)d_in[3];
    const float* W_hh     = (const float*)d_in[4];
    const float* b_ih     = (const float*)d_in[5];
    const float* b_hh     = (const float*)d_in[6];
    float* out = (float*)d_out;

    const int B = in_sizes[0];                  // 100000
    const int N = in_sizes[2] / GRU_H;          // 500000
    const int nwords = (N + 31) / 32;

    bf16x8*   frags  = (bf16x8*)((char*)d_ws + 1024);
    unsigned* bitmap = (unsigned*)((char*)d_ws + 256 * 1024);

    // 1) weights -> bf16 fragments + clear bitmap
    prep_weights<<<24, 512, 0, stream>>>(W_ih, W_hh, frags, bitmap, nwords);
    // 2) mark scatter targets
    set_bits<<<(B + 511) / 512, 512, 0, stream>>>(node_ids, B, bitmap);
    // 3) fused GRU + copy
    fused_kernel<<<512, 512, 0, stream>>>(node_ids, messages, memory, frags,
                                          b_ih, b_hh, bitmap, out, B, N);
}